// Round 2
// baseline (129.098 us; speedup 1.0000x reference)
//
#include <hip/hip_runtime.h>
#include <math.h>

// Problem constants (from reference setup_inputs):
// B=4, N=65536, IN=2, OUT=512, C=64, H=32, W=32, W0=30
#define SIREN_W0 30.0f

typedef float f32x4 __attribute__((ext_vector_type(4)));
typedef float f32x2 __attribute__((ext_vector_type(2)));

// ---------------------------------------------------------------------------
// Kernel 1: combined[pos][o] = sum_c latent[b,c,y,x]*W_shift[o,c] + b_shift[o]
//                            + sum_c v[b,c,y,x]*W_vshift[o,c]     + b_vshift[o]
// pos = b*1024 + y*32 + x  (4096 positions), o in [0,512)
// Both gathers in the reference use the SAME (iy,ix), so one combined map
// suffices. 16 positions per block; feat staged in LDS (reads are
// uniform-address broadcasts -> no bank conflicts); 4-out x 8-pos reg tile.
// ---------------------------------------------------------------------------
__global__ __launch_bounds__(256) void build_combined(
    const float* __restrict__ latent, const float* __restrict__ v,
    const float* __restrict__ W_shift, const float* __restrict__ b_shift,
    const float* __restrict__ W_vshift, const float* __restrict__ b_vshift,
    float* __restrict__ combined)
{
    __shared__ float featL[16][64];
    __shared__ float featV[16][64];
    const int pos0 = blockIdx.x * 16;
    const int b    = pos0 >> 10;        // 1024 positions per batch
    const int rem  = pos0 & 1023;       // y*32 + x0, x0 in {0,16}
    const int t    = threadIdx.x;

    // Stage latent[b,:,y,x0..x0+15] and v likewise: 64 ch x 16 pos each.
    // element e: c = e>>4, p = e&15 ; global addr = base + c*1024 + p
    const float* latBase = latent + (size_t)b * 65536 + rem;
    const float* vBase   = v      + (size_t)b * 65536 + rem;
#pragma unroll
    for (int k = 0; k < 4; ++k) {
        int e = t + k * 256;
        int c = e >> 4, p = e & 15;
        featL[p][c] = latBase[c * 1024 + p];
        featV[p][c] = vBase[c * 1024 + p];
    }
    __syncthreads();

    const int og = t & 127;   // 128 output-groups of 4
    const int pg = t >> 7;    // 2 position-groups of 8
    const int o0 = og * 4;
    const int p0 = pg * 8;

    float acc[8][4];
#pragma unroll
    for (int j = 0; j < 4; ++j) {
        float binit = b_shift[o0 + j] + b_vshift[o0 + j];
#pragma unroll
        for (int p = 0; p < 8; ++p) acc[p][j] = binit;
    }

    const f32x4* WS = (const f32x4*)(W_shift  + (size_t)o0 * 64);
    const f32x4* WV = (const f32x4*)(W_vshift + (size_t)o0 * 64);

#pragma unroll 4
    for (int c4 = 0; c4 < 16; ++c4) {
        f32x4 wS[4], wV[4];
#pragma unroll
        for (int j = 0; j < 4; ++j) {
            wS[j] = WS[j * 16 + c4];   // row o0+j, channels c4*4..+3
            wV[j] = WV[j * 16 + c4];
        }
#pragma unroll
        for (int p = 0; p < 8; ++p) {
            f32x4 fL = *(const f32x4*)&featL[p0 + p][c4 * 4];
            f32x4 fV = *(const f32x4*)&featV[p0 + p][c4 * 4];
#pragma unroll
            for (int j = 0; j < 4; ++j) {
                acc[p][j] += fL.x * wS[j].x + fL.y * wS[j].y
                           + fL.z * wS[j].z + fL.w * wS[j].w
                           + fV.x * wV[j].x + fV.y * wV[j].y
                           + fV.z * wV[j].z + fV.w * wV[j].w;
            }
        }
    }

#pragma unroll
    for (int p = 0; p < 8; ++p) {
        f32x4 r = { acc[p][0], acc[p][1], acc[p][2], acc[p][3] };
        *(f32x4*)(combined + (size_t)(pos0 + p0 + p) * 512 + o0) = r;
    }
}

// ---------------------------------------------------------------------------
// Kernel 2: out[point, o] = sin(30*(h[point,o] + combined[b,iy,ix,o]))
// h[point,o] = x0*W_lin[o,0] + x1*W_lin[o,1] + b_lin[o]
// (iy,ix) from h channels 0/1: round-half-even then clip to [0,31].
// One thread per float4 of output (128 threads per point).
// ---------------------------------------------------------------------------
__global__ __launch_bounds__(256) void siren_out(
    const float* __restrict__ x, const float* __restrict__ W_lin,
    const float* __restrict__ b_lin, const float* __restrict__ combined,
    float* __restrict__ out)
{
    const int task  = blockIdx.x * 256 + threadIdx.x;
    const int point = task >> 7;        // [0, 262144)
    const int chunk = task & 127;       // float4 index within 512 outputs
    const int b     = point >> 16;      // N = 65536 points per batch

    const f32x2 xv = *(const f32x2*)(x + (size_t)point * 2);

    // coordinate channels (rows 0 and 1 of W_lin, [512][2] row-major)
    const f32x4 wl = *(const f32x4*)W_lin;   // w00 w01 w10 w11
    const f32x2 bl = *(const f32x2*)b_lin;
    const float h0 = xv.x * wl.x + xv.y * wl.y + bl.x;
    const float h1 = xv.x * wl.z + xv.y * wl.w + bl.y;

    // ix from channel 0 (W dim), iy from channel 1 (H dim); W-1 = H-1 = 31
    const float fx = (h0 + 1.0f) * 0.5f * 31.0f;
    const float fy = (h1 + 1.0f) * 0.5f * 31.0f;
    int ix = (int)rintf(fx); ix = ix < 0 ? 0 : (ix > 31 ? 31 : ix);
    int iy = (int)rintf(fy); iy = iy < 0 ? 0 : (iy > 31 ? 31 : iy);

    const f32x4* crow =
        (const f32x4*)(combined + (size_t)(((b << 5) + iy) * 32 + ix) * 512);
    const f32x4 c4 = crow[chunk];

    // W_lin rows o0..o0+3 (o0 = chunk*4): two float4s of [w,o0],[w,o0+1],...
    const f32x4 wA = ((const f32x4*)W_lin)[chunk * 2];
    const f32x4 wB = ((const f32x4*)W_lin)[chunk * 2 + 1];
    const f32x4 bb = ((const f32x4*)b_lin)[chunk];

    f32x4 r;
    r.x = __sinf(SIREN_W0 * (xv.x * wA.x + xv.y * wA.y + bb.x + c4.x));
    r.y = __sinf(SIREN_W0 * (xv.x * wA.z + xv.y * wA.w + bb.y + c4.y));
    r.z = __sinf(SIREN_W0 * (xv.x * wB.x + xv.y * wB.y + bb.z + c4.z));
    r.w = __sinf(SIREN_W0 * (xv.x * wB.z + xv.y * wB.w + bb.w + c4.w));

    __builtin_nontemporal_store(r, ((f32x4*)out) + task);
}

extern "C" void kernel_launch(void* const* d_in, const int* in_sizes, int n_in,
                              void* d_out, int out_size, void* d_ws, size_t ws_size,
                              hipStream_t stream) {
    const float* x        = (const float*)d_in[0];
    const float* latent   = (const float*)d_in[1];
    const float* v        = (const float*)d_in[2];
    const float* W_lin    = (const float*)d_in[3];
    const float* b_lin    = (const float*)d_in[4];
    const float* W_shift  = (const float*)d_in[5];
    const float* b_shift  = (const float*)d_in[6];
    const float* W_vshift = (const float*)d_in[7];
    const float* b_vshift = (const float*)d_in[8];
    float* out      = (float*)d_out;
    float* combined = (float*)d_ws;   // needs 4*32*32*512*4 = 8 MiB of d_ws

    // Kernel 1: 4096 positions / 16 per block = 256 blocks
    build_combined<<<256, 256, 0, stream>>>(latent, v, W_shift, b_shift,
                                            W_vshift, b_vshift, combined);

    // Kernel 2: 262144 points * 128 float4-chunks / 256 threads = 131072 blocks
    siren_out<<<131072, 256, 0, stream>>>(x, W_lin, b_lin, combined, out);
}

// Round 3
// 115.345 us; speedup vs baseline: 1.1192x; 1.1192x over previous
//
#include <hip/hip_runtime.h>
#include <math.h>

// Problem constants (from reference setup_inputs):
// B=4, N=65536, IN=2, OUT=512, C=64, H=32, W=32, W0=30
#define SIREN_W0 30.0f

typedef float f32x4 __attribute__((ext_vector_type(4)));
typedef float f32x2 __attribute__((ext_vector_type(2)));

// ---------------------------------------------------------------------------
// Kernel 1: combined[pos][o] = sum_c latent[b,c,y,x]*W_shift[o,c] + b_shift[o]
//                            + sum_c v[b,c,y,x]*W_vshift[o,c]     + b_vshift[o]
// pos = b*1024 + y*32 + x  (4096 positions), o in [0,512)
// Both gathers in the reference use the SAME (iy,ix), so one combined map
// suffices. 16 positions per block; feat staged in LDS (reads are
// uniform-address broadcasts -> no bank conflicts); 4-out x 8-pos reg tile.
// ---------------------------------------------------------------------------
__global__ __launch_bounds__(256) void build_combined(
    const float* __restrict__ latent, const float* __restrict__ v,
    const float* __restrict__ W_shift, const float* __restrict__ b_shift,
    const float* __restrict__ W_vshift, const float* __restrict__ b_vshift,
    float* __restrict__ combined)
{
    __shared__ float featL[16][64];
    __shared__ float featV[16][64];
    const int pos0 = blockIdx.x * 16;
    const int b    = pos0 >> 10;        // 1024 positions per batch
    const int rem  = pos0 & 1023;       // y*32 + x0, x0 in {0,16}
    const int t    = threadIdx.x;

    const float* latBase = latent + (size_t)b * 65536 + rem;
    const float* vBase   = v      + (size_t)b * 65536 + rem;
#pragma unroll
    for (int k = 0; k < 4; ++k) {
        int e = t + k * 256;
        int c = e >> 4, p = e & 15;
        featL[p][c] = latBase[c * 1024 + p];
        featV[p][c] = vBase[c * 1024 + p];
    }
    __syncthreads();

    const int og = t & 127;   // 128 output-groups of 4
    const int pg = t >> 7;    // 2 position-groups of 8
    const int o0 = og * 4;
    const int p0 = pg * 8;

    float acc[8][4];
#pragma unroll
    for (int j = 0; j < 4; ++j) {
        float binit = b_shift[o0 + j] + b_vshift[o0 + j];
#pragma unroll
        for (int p = 0; p < 8; ++p) acc[p][j] = binit;
    }

    const f32x4* WS = (const f32x4*)(W_shift  + (size_t)o0 * 64);
    const f32x4* WV = (const f32x4*)(W_vshift + (size_t)o0 * 64);

#pragma unroll 4
    for (int c4 = 0; c4 < 16; ++c4) {
        f32x4 wS[4], wV[4];
#pragma unroll
        for (int j = 0; j < 4; ++j) {
            wS[j] = WS[j * 16 + c4];   // row o0+j, channels c4*4..+3
            wV[j] = WV[j * 16 + c4];
        }
#pragma unroll
        for (int p = 0; p < 8; ++p) {
            f32x4 fL = *(const f32x4*)&featL[p0 + p][c4 * 4];
            f32x4 fV = *(const f32x4*)&featV[p0 + p][c4 * 4];
#pragma unroll
            for (int j = 0; j < 4; ++j) {
                acc[p][j] += fL.x * wS[j].x + fL.y * wS[j].y
                           + fL.z * wS[j].z + fL.w * wS[j].w
                           + fV.x * wV[j].x + fV.y * wV[j].y
                           + fV.z * wV[j].z + fV.w * wV[j].w;
            }
        }
    }

#pragma unroll
    for (int p = 0; p < 8; ++p) {
        f32x4 r = { acc[p][0], acc[p][1], acc[p][2], acc[p][3] };
        *(f32x4*)(combined + (size_t)(pos0 + p0 + p) * 512 + o0) = r;
    }
}

// ---------------------------------------------------------------------------
// Kernel 2: out[point, o] = sin(30*(h[point,o] + combined[b,iy,ix,o]))
// h[point,o] = x0*W_lin[o,0] + x1*W_lin[o,1] + b_lin[o]
// (iy,ix) from h channels 0/1: round-half-even then clip to [0,31].
// 32 threads per point; each thread handles 4 float4 chunks
// (lane, lane+32, lane+64, lane+96) = 64 B stored per thread.
// Store instruction k: half-wave writes contiguous 512 B per point row.
// ---------------------------------------------------------------------------
__global__ __launch_bounds__(256) void siren_out(
    const float* __restrict__ x, const float* __restrict__ W_lin,
    const float* __restrict__ b_lin, const float* __restrict__ combined,
    float* __restrict__ out)
{
    const int tid   = blockIdx.x * 256 + threadIdx.x;  // [0, 8388608)
    const int point = tid >> 5;         // 32 threads per point, 262144 points
    const int lane  = tid & 31;
    const int b     = point >> 16;      // N = 65536 points per batch

    const f32x2 xv = *(const f32x2*)(x + (size_t)point * 2);

    // coordinate channels (rows 0 and 1 of W_lin, [512][2] row-major)
    const f32x4 wl = *(const f32x4*)W_lin;   // w00 w01 w10 w11
    const f32x2 bl = *(const f32x2*)b_lin;
    const float h0 = xv.x * wl.x + xv.y * wl.y + bl.x;
    const float h1 = xv.x * wl.z + xv.y * wl.w + bl.y;

    // ix from channel 0 (W dim), iy from channel 1 (H dim); W-1 = H-1 = 31
    const float fx = (h0 + 1.0f) * 0.5f * 31.0f;
    const float fy = (h1 + 1.0f) * 0.5f * 31.0f;
    int ix = (int)rintf(fx); ix = ix < 0 ? 0 : (ix > 31 ? 31 : ix);
    int iy = (int)rintf(fy); iy = iy < 0 ? 0 : (iy > 31 ? 31 : iy);

    const f32x4* crow =
        (const f32x4*)(combined + (size_t)(((b << 5) + iy) * 32 + ix) * 512);
    const f32x4* Wl4 = (const f32x4*)W_lin;
    const f32x4* Bl4 = (const f32x4*)b_lin;
    f32x4* orow = ((f32x4*)out) + (size_t)point * 128;

#pragma unroll
    for (int k = 0; k < 4; ++k) {
        const int chunk = lane + k * 32;
        const f32x4 c4 = crow[chunk];
        const f32x4 wA = Wl4[chunk * 2];
        const f32x4 wB = Wl4[chunk * 2 + 1];
        const f32x4 bb = Bl4[chunk];

        f32x4 r;
        r.x = __sinf(SIREN_W0 * (xv.x * wA.x + xv.y * wA.y + bb.x + c4.x));
        r.y = __sinf(SIREN_W0 * (xv.x * wA.z + xv.y * wA.w + bb.y + c4.y));
        r.z = __sinf(SIREN_W0 * (xv.x * wB.x + xv.y * wB.y + bb.z + c4.z));
        r.w = __sinf(SIREN_W0 * (xv.x * wB.z + xv.y * wB.w + bb.w + c4.w));

        __builtin_nontemporal_store(r, orow + chunk);
    }
}

extern "C" void kernel_launch(void* const* d_in, const int* in_sizes, int n_in,
                              void* d_out, int out_size, void* d_ws, size_t ws_size,
                              hipStream_t stream) {
    const float* x        = (const float*)d_in[0];
    const float* latent   = (const float*)d_in[1];
    const float* v        = (const float*)d_in[2];
    const float* W_lin    = (const float*)d_in[3];
    const float* b_lin    = (const float*)d_in[4];
    const float* W_shift  = (const float*)d_in[5];
    const float* b_shift  = (const float*)d_in[6];
    const float* W_vshift = (const float*)d_in[7];
    const float* b_vshift = (const float*)d_in[8];
    float* out      = (float*)d_out;
    float* combined = (float*)d_ws;   // needs 4*32*32*512*4 = 8 MiB of d_ws

    // Kernel 1: 4096 positions / 16 per block = 256 blocks
    build_combined<<<256, 256, 0, stream>>>(latent, v, W_shift, b_shift,
                                            W_vshift, b_vshift, combined);

    // Kernel 2: 262144 points * 32 threads / 256 = 32768 blocks
    siren_out<<<32768, 256, 0, stream>>>(x, W_lin, b_lin, combined, out);
}

// Round 4
// 115.163 us; speedup vs baseline: 1.1210x; 1.0016x over previous
//
#include <hip/hip_runtime.h>
#include <math.h>

// Problem constants (from reference setup_inputs):
// B=4, N=65536, IN=2, OUT=512, C=64, H=32, W=32, W0=30
#define SIREN_W0 30.0f

typedef float f32x4 __attribute__((ext_vector_type(4)));
typedef float f32x2 __attribute__((ext_vector_type(2)));

// ---------------------------------------------------------------------------
// Kernel 1: combined[pos][o] = sum_c latent[b,c,y,x]*W_shift[o,c] + b_shift[o]
//                            + sum_c v[b,c,y,x]*W_vshift[o,c]     + b_vshift[o]
// pos = b*1024 + y*32 + x  (4096 positions), o in [0,512)
// Both gathers in the reference use the SAME (iy,ix), so one combined map
// suffices. 16 positions per block; feat staged in LDS; 4-out x 8-pos tile.
// ---------------------------------------------------------------------------
__global__ __launch_bounds__(256) void build_combined(
    const float* __restrict__ latent, const float* __restrict__ v,
    const float* __restrict__ W_shift, const float* __restrict__ b_shift,
    const float* __restrict__ W_vshift, const float* __restrict__ b_vshift,
    float* __restrict__ combined)
{
    __shared__ float featL[16][64];
    __shared__ float featV[16][64];
    const int pos0 = blockIdx.x * 16;
    const int b    = pos0 >> 10;        // 1024 positions per batch
    const int rem  = pos0 & 1023;       // y*32 + x0, x0 in {0,16}
    const int t    = threadIdx.x;

    const float* latBase = latent + (size_t)b * 65536 + rem;
    const float* vBase   = v      + (size_t)b * 65536 + rem;
#pragma unroll
    for (int k = 0; k < 4; ++k) {
        int e = t + k * 256;
        int c = e >> 4, p = e & 15;
        featL[p][c] = latBase[c * 1024 + p];
        featV[p][c] = vBase[c * 1024 + p];
    }
    __syncthreads();

    const int og = t & 127;   // 128 output-groups of 4
    const int pg = t >> 7;    // 2 position-groups of 8
    const int o0 = og * 4;
    const int p0 = pg * 8;

    float acc[8][4];
#pragma unroll
    for (int j = 0; j < 4; ++j) {
        float binit = b_shift[o0 + j] + b_vshift[o0 + j];
#pragma unroll
        for (int p = 0; p < 8; ++p) acc[p][j] = binit;
    }

    const f32x4* WS = (const f32x4*)(W_shift  + (size_t)o0 * 64);
    const f32x4* WV = (const f32x4*)(W_vshift + (size_t)o0 * 64);

#pragma unroll 4
    for (int c4 = 0; c4 < 16; ++c4) {
        f32x4 wS[4], wV[4];
#pragma unroll
        for (int j = 0; j < 4; ++j) {
            wS[j] = WS[j * 16 + c4];   // row o0+j, channels c4*4..+3
            wV[j] = WV[j * 16 + c4];
        }
#pragma unroll
        for (int p = 0; p < 8; ++p) {
            f32x4 fL = *(const f32x4*)&featL[p0 + p][c4 * 4];
            f32x4 fV = *(const f32x4*)&featV[p0 + p][c4 * 4];
#pragma unroll
            for (int j = 0; j < 4; ++j) {
                acc[p][j] += fL.x * wS[j].x + fL.y * wS[j].y
                           + fL.z * wS[j].z + fL.w * wS[j].w
                           + fV.x * wV[j].x + fV.y * wV[j].y
                           + fV.z * wV[j].z + fV.w * wV[j].w;
            }
        }
    }

#pragma unroll
    for (int p = 0; p < 8; ++p) {
        f32x4 r = { acc[p][0], acc[p][1], acc[p][2], acc[p][3] };
        *(f32x4*)(combined + (size_t)(pos0 + p0 + p) * 512 + o0) = r;
    }
}

// ---------------------------------------------------------------------------
// Kernel 2: out[point, o] = sin(30*(h[point,o] + combined[b,iy,ix,o]))
// 32 threads per point; each thread handles 4 float4 chunks (64 B stored).
//
// XCD-aware swizzle: blocks dispatch round-robin across the 8 XCDs
// (xcd = bid & 7). We remap so XCD k processes ONLY batch k/2:
// per-XCD gather working set = 2 MiB (one batch's combined rows), which
// fits the 4 MiB per-XCD L2 -> gather reads served from L2, not L3.
// Mapping is bijective over 32768 blocks; if the xcd assumption is wrong
// this degrades to the previous behavior, never to incorrectness.
// ---------------------------------------------------------------------------
__global__ __launch_bounds__(256) void siren_out(
    const float* __restrict__ x, const float* __restrict__ W_lin,
    const float* __restrict__ b_lin, const float* __restrict__ combined,
    float* __restrict__ out)
{
    const int bid = blockIdx.x;
    const int xcd = bid & 7;
    const int idx = bid >> 3;                              // [0, 4096)
    const int pb  = ((xcd >> 1) << 13) + ((xcd & 1) << 12) + idx; // [0, 32768)

    const int tid   = pb * 256 + threadIdx.x;  // [0, 8388608)
    const int point = tid >> 5;         // 32 threads per point, 262144 points
    const int lane  = tid & 31;
    const int b     = point >> 16;      // N = 65536 points per batch

    const f32x2 xv = *(const f32x2*)(x + (size_t)point * 2);

    // coordinate channels (rows 0 and 1 of W_lin, [512][2] row-major)
    const f32x4 wl = *(const f32x4*)W_lin;   // w00 w01 w10 w11
    const f32x2 bl = *(const f32x2*)b_lin;
    const float h0 = xv.x * wl.x + xv.y * wl.y + bl.x;
    const float h1 = xv.x * wl.z + xv.y * wl.w + bl.y;

    // ix from channel 0 (W dim), iy from channel 1 (H dim); W-1 = H-1 = 31
    const float fx = (h0 + 1.0f) * 0.5f * 31.0f;
    const float fy = (h1 + 1.0f) * 0.5f * 31.0f;
    int ix = (int)rintf(fx); ix = ix < 0 ? 0 : (ix > 31 ? 31 : ix);
    int iy = (int)rintf(fy); iy = iy < 0 ? 0 : (iy > 31 ? 31 : iy);

    const f32x4* crow =
        (const f32x4*)(combined + (size_t)(((b << 5) + iy) * 32 + ix) * 512);
    const f32x4* Wl4 = (const f32x4*)W_lin;
    const f32x4* Bl4 = (const f32x4*)b_lin;
    f32x4* orow = ((f32x4*)out) + (size_t)point * 128;

#pragma unroll
    for (int k = 0; k < 4; ++k) {
        const int chunk = lane + k * 32;
        const f32x4 c4 = crow[chunk];
        const f32x4 wA = Wl4[chunk * 2];
        const f32x4 wB = Wl4[chunk * 2 + 1];
        const f32x4 bb = Bl4[chunk];

        f32x4 r;
        r.x = __sinf(SIREN_W0 * (xv.x * wA.x + xv.y * wA.y + bb.x + c4.x));
        r.y = __sinf(SIREN_W0 * (xv.x * wA.z + xv.y * wA.w + bb.y + c4.y));
        r.z = __sinf(SIREN_W0 * (xv.x * wB.x + xv.y * wB.y + bb.z + c4.z));
        r.w = __sinf(SIREN_W0 * (xv.x * wB.z + xv.y * wB.w + bb.w + c4.w));

        __builtin_nontemporal_store(r, orow + chunk);
    }
}

extern "C" void kernel_launch(void* const* d_in, const int* in_sizes, int n_in,
                              void* d_out, int out_size, void* d_ws, size_t ws_size,
                              hipStream_t stream) {
    const float* x        = (const float*)d_in[0];
    const float* latent   = (const float*)d_in[1];
    const float* v        = (const float*)d_in[2];
    const float* W_lin    = (const float*)d_in[3];
    const float* b_lin    = (const float*)d_in[4];
    const float* W_shift  = (const float*)d_in[5];
    const float* b_shift  = (const float*)d_in[6];
    const float* W_vshift = (const float*)d_in[7];
    const float* b_vshift = (const float*)d_in[8];
    float* out      = (float*)d_out;
    float* combined = (float*)d_ws;   // needs 4*32*32*512*4 = 8 MiB of d_ws

    // Kernel 1: 4096 positions / 16 per block = 256 blocks
    build_combined<<<256, 256, 0, stream>>>(latent, v, W_shift, b_shift,
                                            W_vshift, b_vshift, combined);

    // Kernel 2: 262144 points * 32 threads / 256 = 32768 blocks
    siren_out<<<32768, 256, 0, stream>>>(x, W_lin, b_lin, combined, out);
}